// Round 21
// baseline (42.565 us; speedup 1.0000x reference)
//
#include <hip/hip_runtime.h>
#include <hip/hip_bf16.h>
#include <cstdint>

// PiNet: B=8192, I=12, O=512, DEG=4.
// R20: R19 base; fold's per-term gather ADDRESSES precomputed at compile time
// (constexpr rodata: AD4[1365][24], AD3[364][8] -- u16 BYTE offsets into the
// padded LDS layouts). Inner loop: 3 coalesced uint4 table loads + unpack +
// ds_read_u16, replacing ~72 VALU mad/extract per t. Gemm identical to R18.

#define NB 8192
#define NI 12
#define NO 512
#define T_TOTAL 1820
#define TPAD 1920          // 15 * 128
#define NKT 15
#define B2 13
#define B3 91
#define B4 455

// padded LDS strides for staged w4/w3 (u16 units)
#define P4S 1780
#define Q4S 148
#define P3S 148

typedef __attribute__((ext_vector_type(8))) _Float16 f16x8;
typedef __attribute__((ext_vector_type(4))) float f32x4;

#define MFMA16(a, b, c) __builtin_amdgcn_mfma_f32_16x16x32_f16(a, b, c, 0, 0, 0)

__device__ __forceinline__ unsigned short f2h(float f) {
    _Float16 h = (_Float16)f;
    return __builtin_bit_cast(unsigned short, h);
}
__device__ __forceinline__ float h2f(unsigned short u) {
    return (float)__builtin_bit_cast(_Float16, u);
}

// ---------- compile-time tables ----------
constexpr int H2c(int n) { return n * (n + 1) / 2; }
constexpr int H3c(int n) { return n * (n + 1) * (n + 2) / 6; }
constexpr int rank2c(int a, int b) {
    int r = 0;
    for (int j = 0; j < a; ++j) r += NI - j;
    return r + (b - a);
}

struct alignas(16) MPArr { uint32_t v[TPAD]; };
constexpr MPArr gen_mp() {
    MPArr m{};
    for (int t = 0; t < TPAD; ++t) {
        uint32_t v = 0;
        if (t == 0) {
            v = 0;
        } else if (t < B2) {
            v = (uint32_t)t;
        } else if (t < B3) {
            int r = t - B2, a = 0;
            while (r >= NI - a) { r -= NI - a; ++a; }
            int b = a + r;
            v = (uint32_t)(1 + a) | ((uint32_t)(1 + b) << 16);
        } else if (t < B4) {
            int r = t - B3, a = 0;
            while (r >= H2c(NI - a)) { r -= H2c(NI - a); ++a; }
            int b = a;
            while (r >= NI - b) { r -= NI - b; ++b; }
            int c = b + r;
            v = (uint32_t)(13 + rank2c(a, b)) | ((uint32_t)(1 + c) << 16);
        } else if (t < T_TOTAL) {
            int r = t - B4, a = 0;
            while (r >= H3c(NI - a)) { r -= H3c(NI - a); ++a; }
            int b = a;
            while (r >= H2c(NI - b)) { r -= H2c(NI - b); ++b; }
            int c = b;
            while (r >= NI - c) { r -= NI - c; ++c; }
            int d = c + r;
            v = (uint32_t)(13 + rank2c(a, b)) | ((uint32_t)(13 + rank2c(c, d)) << 16);
        }
        m.v[t] = v;          // t in [1820,1920): monomial = 1, weight 0
    }
    return m;
}
__device__ constexpr MPArr MP = gen_mp();

// per-t gather BYTE-offset tables (into padded sw4h/sw3h) + rk weights
struct alignas(16) AD4Arr { uint16_t v[1365 * 24]; };
constexpr AD4Arr gen_ad4() {
    AD4Arr t{};
    int q = 0;
    for (int a = 0; a < 12; ++a)
        for (int b = a; b < 12; ++b)
            for (int c = b; c < 12; ++c)
                for (int d = c; d < 12; ++d) {
                    int vals[4] = {a, b, c, d};
                    int n = 0;
                    for (int p0 = 0; p0 < 4; ++p0)
                        for (int p1 = 0; p1 < 4; ++p1) {
                            if (p1 == p0) continue;
                            for (int p2 = 0; p2 < 4; ++p2) {
                                if (p2 == p0 || p2 == p1) continue;
                                int p3 = 6 - p0 - p1 - p2;
                                t.v[q * 24 + n++] = (uint16_t)(2 *
                                    (vals[p0] * P4S + vals[p1] * Q4S +
                                     vals[p2] * 12 + vals[p3]));
                            }
                        }
                    ++q;
                }
    return t;
}
__device__ constexpr AD4Arr AD4 = gen_ad4();

struct alignas(16) AD3Arr { uint16_t v[364 * 8]; };
constexpr AD3Arr gen_ad3() {
    AD3Arr t{};
    int q = 0;
    for (int a = 0; a < 12; ++a)
        for (int b = a; b < 12; ++b)
            for (int c = b; c < 12; ++c) {
                int vals[3] = {a, b, c};
                int n = 0;
                for (int p0 = 0; p0 < 3; ++p0)
                    for (int p1 = 0; p1 < 3; ++p1) {
                        if (p1 == p0) continue;
                        int p2 = 3 - p0 - p1;
                        t.v[q * 8 + n++] = (uint16_t)(2 *
                            (vals[p0] * P3S + vals[p1] * 12 + vals[p2]));
                    }
                t.v[q * 8 + 6] = 0; t.v[q * 8 + 7] = 0;   // pad, never summed
                ++q;
            }
    return t;
}
__device__ constexpr AD3Arr AD3 = gen_ad3();

struct FoldArr {
    uint16_t tup2[78];  float rk2[78];
    float rk3[364];
    float rk4[1368];
};
constexpr FoldArr gen_fold() {
    FoldArr f{};
    for (int q = 0; q < 78; ++q) {
        int r = q, a = 0;
        while (r >= NI - a) { r -= NI - a; ++a; }
        int b = a + r;
        f.tup2[q] = (uint16_t)(a | (b << 4));
        f.rk2[q] = (a == b) ? 0.5f : 1.0f;
    }
    {
        int q = 0;
        for (int a = 0; a < 12; ++a)
            for (int b = a; b < 12; ++b)
                for (int c = b; c < 12; ++c) {
                    int k = 1, run = 1;
                    if (b == a) { ++run; k *= run; } else run = 1;
                    if (c == b) { ++run; k *= run; } else run = 1;
                    f.rk3[q++] = 1.0f / (float)k;
                }
    }
    {
        int q = 0;
        for (int a = 0; a < 12; ++a)
            for (int b = a; b < 12; ++b)
                for (int c = b; c < 12; ++c)
                    for (int d = c; d < 12; ++d) {
                        int k = 1, run = 1;
                        if (b == a) { ++run; k *= run; } else run = 1;
                        if (c == b) { ++run; k *= run; } else run = 1;
                        if (d == c) { ++run; k *= run; } else run = 1;
                        f.rk4[q++] = 1.0f / (float)k;
                    }
    }
    return f;
}
__device__ constexpr FoldArr FT = gen_fold();

// ---------- fold: fp16 LDS staging (padded strides) + table-driven gather -----
__global__ __launch_bounds__(1024, 8) void pinet_fold(
    const float* __restrict__ w0, const float* __restrict__ w1,
    const float* __restrict__ w2, const float* __restrict__ w3,
    const float* __restrict__ w4, ushort* __restrict__ Wh) {
    __shared__ ushort sw4h[12 * P4S];   // strides (1780,148,12,1) u16
    __shared__ ushort sw3h[12 * P3S];   // strides (148,12,1) u16
    __shared__ ushort sw2h[144];
    const int tid = threadIdx.x;
    const int o = blockIdx.x;

    {   // coalesced staging, f32 -> fp16, remapped to padded layout
        const float4* g4 = (const float4*)(w4 + o * 20736);
        for (int i = tid; i < 5184; i += 1024) {
            float4 v = g4[i];
            int c0 = i * 4;
            int p = c0 / 1728, rem = c0 % 1728;
            int q = rem / 144, r2 = rem % 144;
            int r = r2 / 12, s0 = r2 % 12;
            ushort4 h = {f2h(v.x), f2h(v.y), f2h(v.z), f2h(v.w)};
            *(ushort4*)&sw4h[p * P4S + q * Q4S + r * 12 + s0] = h;
        }
        if (tid < 432) {
            float4 v = ((const float4*)(w3 + o * 1728))[tid];
            int c0 = tid * 4;
            int a = c0 / 144, rem = c0 % 144;
            int b = rem / 12, s0 = rem % 12;
            ushort4 h = {f2h(v.x), f2h(v.y), f2h(v.z), f2h(v.w)};
            *(ushort4*)&sw3h[a * P3S + b * 12 + s0] = h;
        }
        if (tid < 36) {
            float4 v = ((const float4*)(w2 + o * 144))[tid];
            ushort4 h = {f2h(v.x), f2h(v.y), f2h(v.z), f2h(v.w)};
            *(ushort4*)&sw2h[tid * 4] = h;
        }
    }
    __syncthreads();

    const char* s4b = (const char*)sw4h;
    const char* s3b = (const char*)sw3h;
    for (int t = tid; t < TPAD; t += 1024) {
        float s = 0.0f;
        if (t == 0) {
            s = w0[o];
        } else if (t < B2) {
            s = w1[o * 12 + (t - 1)];
        } else if (t < B3) {
            int q = t - B2; int tp = FT.tup2[q];
            int a = tp & 15, b = (tp >> 4) & 15;
            s = (h2f(sw2h[a * 12 + b]) + h2f(sw2h[b * 12 + a])) * FT.rk2[q];
        } else if (t < B4) {
            int q = t - B3;
            uint4 A0 = *(const uint4*)&AD3.v[q * 8];
            uint32_t w_[3] = {A0.x, A0.y, A0.z};
            float acc3 = 0.0f;
#pragma unroll
            for (int j = 0; j < 3; ++j) {
                acc3 += h2f(*(const ushort*)(s3b + (w_[j] & 0xFFFFu)));
                acc3 += h2f(*(const ushort*)(s3b + (w_[j] >> 16)));
            }
            s = acc3 * FT.rk3[q];
        } else if (t < T_TOTAL) {
            int q = t - B4;
            const uint4* ad = (const uint4*)&AD4.v[q * 24];
            uint4 A0 = ad[0], A1 = ad[1], A2 = ad[2];
            uint32_t w_[12] = {A0.x, A0.y, A0.z, A0.w, A1.x, A1.y, A1.z, A1.w,
                               A2.x, A2.y, A2.z, A2.w};
            float acc4 = 0.0f;
#pragma unroll
            for (int j = 0; j < 12; ++j) {
                acc4 += h2f(*(const ushort*)(s4b + (w_[j] & 0xFFFFu)));
                acc4 += h2f(*(const ushort*)(s4b + (w_[j] >> 16)));
            }
            s = acc4 * FT.rk4[q];
        }
        Wh[((t >> 3) * NO + o) * 8 + (t & 7)] = f2h(s);
    }
}

// ---------- MFMA GEMM: identical to R18 (K-split, KT=128) ----------
__global__ __launch_bounds__(1024, 4) void pinet_gemm(
    const float* __restrict__ x, const ushort* __restrict__ Wh,
    float* __restrict__ out) {
    __shared__ __align__(16) uint8_t smem[65536];
    float (*msm)[93] = (float(*)[93])smem;                 // 32*93*4 = 11904 B
    typedef ushort AshT[2][32][16][8];
    AshT& ash = *(AshT*)(smem + 11904);                    // 16384 B -> 28288
    float* red = (float*)smem;                             // 64KB overlay (post-loop)

    const int tid = threadIdx.x;
    const int b0 = blockIdx.x * 32;

    for (int idx = tid; idx < 32 * 13; idx += 1024) {
        int b = idx / 13, j = idx % 13;
        msm[b][j] = (j == 0) ? 1.0f : x[(b0 + b) * 12 + (j - 1)];
    }
    __syncthreads();
    for (int idx = tid; idx < 32 * 78; idx += 1024) {
        int b = idx / 78, q = idx % 78;
        uint32_t m2 = MP.v[B2 + q];
        msm[b][13 + q] = msm[b][m2 & 0xFFFFu] * msm[b][m2 >> 16];
    }

    const int l = tid & 63, wv = tid >> 6;  // 16 waves
    const int lm = l & 15, lg = l >> 4;
    const int kg = wv >> 3, og = wv & 7;    // 2 k-groups x 8 o-groups
    const int o_w = og * 64;
    const int bgen = tid & 31;
    const int task = tid >> 5;              // 0..31, 4 t's each (128 t / kt)
    const int sA = (task >> 1) ^ (bgen & 15);
    const int hOf = (task & 1) * 4;

    f32x4 acc[2][4] = {};                   // [bs][os]
    f16x8 Bv[2][4];                         // [c][os], own K-half only

    auto gen = [&](int kt, int buf) {
        int t0 = kt * 128 + task * 4;
        uint4 mq = *(const uint4*)&MP.v[t0];
        const float* row = msm[bgen];
        uint32_t mqs[4] = {mq.x, mq.y, mq.z, mq.w};
        unsigned short vv[4];
#pragma unroll
        for (int j = 0; j < 4; ++j) {
            float p = row[mqs[j] & 0xFFFFu] * row[mqs[j] >> 16];
            vv[j] = f2h(p);
        }
        ushort4 v = {vv[0], vv[1], vv[2], vv[3]};
        *(ushort4*)&ash[buf][bgen][sA][hOf] = v;
    };
    auto loadB = [&](int kt) {
#pragma unroll
        for (int c = 0; c < 2; ++c)
#pragma unroll
            for (int os = 0; os < 4; ++os) {
                int pk = kt * 16 + kg * 8 + c * 4 + lg;
                Bv[c][os] = *(const f16x8*)(Wh + (pk * NO + o_w + os * 16 + lm) * 8);
            }
    };
    auto mfmaR = [&](int cur) {
#pragma unroll
        for (int c = 0; c < 2; ++c) {
            f16x8 a[2];
#pragma unroll
            for (int bs = 0; bs < 2; ++bs) {
                int br = bs * 16 + lm;
                int oct = kg * 8 + c * 4 + lg;
                a[bs] = *(const f16x8*)&ash[cur][br][oct ^ (br & 15)][0];
            }
#pragma unroll
            for (int bs = 0; bs < 2; ++bs)
#pragma unroll
                for (int os = 0; os < 4; ++os)
                    acc[bs][os] = MFMA16(a[bs], Bv[c][os], acc[bs][os]);
        }
    };

    __syncthreads();          // msm ready
    gen(0, 0);
    __syncthreads();          // ash[0] ready

    for (int kt = 0; kt < NKT; ++kt) {
        const int buf = kt & 1;
        loadB(kt);                        // own K-half; gen covers latency
        if (kt + 1 < NKT) gen(kt + 1, buf ^ 1);
        mfmaR(buf);
        __syncthreads();
    }
    // after final barrier: all msm/ash reads complete -> red overlay is safe

    if (kg == 1) {
#pragma unroll
        for (int bs = 0; bs < 2; ++bs)
#pragma unroll
            for (int os = 0; os < 4; ++os)
                *(f32x4*)&red[(((og * 2 + bs) * 4 + os) * 64 + l) * 4] = acc[bs][os];
    }
    __syncthreads();
    if (kg == 0) {
#pragma unroll
        for (int bs = 0; bs < 2; ++bs)
#pragma unroll
            for (int os = 0; os < 4; ++os) {
                f32x4 v = *(const f32x4*)&red[(((og * 2 + bs) * 4 + os) * 64 + l) * 4];
                acc[bs][os] += v;
                int ob = o_w + os * 16 + lm;
#pragma unroll
                for (int r = 0; r < 4; ++r) {
                    int bb = b0 + bs * 16 + lg * 4 + r;
                    out[bb * NO + ob] = acc[bs][os][r];
                }
            }
    }
}

extern "C" void kernel_launch(void* const* d_in, const int* in_sizes, int n_in,
                              void* d_out, int out_size, void* d_ws, size_t ws_size,
                              hipStream_t stream) {
    const float* x  = (const float*)d_in[0];
    const float* w0 = (const float*)d_in[1];
    const float* w1 = (const float*)d_in[2];
    const float* w2 = (const float*)d_in[3];
    const float* w3 = (const float*)d_in[4];
    const float* w4 = (const float*)d_in[5];
    float* out = (float*)d_out;

    ushort* Wh = (ushort*)d_ws;            // 240*512*8*2 = 1,966,080 B

    pinet_fold<<<NO, 1024, 0, stream>>>(w0, w1, w2, w3, w4, Wh);
    pinet_gemm<<<NB / 32, 1024, 0, stream>>>(x, Wh, out);
}